// Round 2
// baseline (13755.759 us; speedup 1.0000x reference)
//
#include <hip/hip_runtime.h>
#include <math.h>
#include <stdint.h>

#define B_ 16
#define T_ 512
#define C_ 1024
#define H_ 16
#define D_ 64
#define F_ 4096
#define L_ 12
#define M_ 8192  // B*T

typedef __bf16 bf16;
typedef __bf16 bf16x4 __attribute__((ext_vector_type(4)));
typedef __bf16 bf16x8 __attribute__((ext_vector_type(8)));
typedef float f32x4 __attribute__((ext_vector_type(4)));

// ------------------------------------------------------------------
// embed: x[b*T+t, c] = tok[idx[b,t], c] + pos[t, c]   (fp32 in/out)
// ------------------------------------------------------------------
__global__ __launch_bounds__(256) void embed_k(
    const int* __restrict__ idx, const float* __restrict__ tok,
    const float* __restrict__ pos, float* __restrict__ x)
{
  int row = blockIdx.x;          // 0..8191
  int t = row & (T_ - 1);
  int token = idx[row];
  int c = threadIdx.x * 4;
  f32x4 tv = *(const f32x4*)(tok + (size_t)token * C_ + c);
  f32x4 pv = *(const f32x4*)(pos + (size_t)t * C_ + c);
  f32x4 o = tv + pv;
  *(f32x4*)(x + (size_t)row * C_ + c) = o;
}

// ------------------------------------------------------------------
// block reduce (2 values) over 256 threads
// ------------------------------------------------------------------
__device__ __forceinline__ void bredux2(float& a, float& b, float* red)
{
  int lane = threadIdx.x & 63, wid = threadIdx.x >> 6;
#pragma unroll
  for (int off = 32; off > 0; off >>= 1) {
    a += __shfl_down(a, off);
    b += __shfl_down(b, off);
  }
  __syncthreads();               // protect red from prior use
  if (lane == 0) { red[wid] = a; red[4 + wid] = b; }
  __syncthreads();
  a = red[0] + red[1] + red[2] + red[3];
  b = red[4] + red[5] + red[6] + red[7];
}

// ------------------------------------------------------------------
// layernorm: fp32 in -> bf16 out. one block per row, 256 thr x 4 elems
// ------------------------------------------------------------------
__global__ __launch_bounds__(256) void ln_k(
    const float* __restrict__ x, const float* __restrict__ w,
    const float* __restrict__ b, bf16* __restrict__ out)
{
  __shared__ float red[8];
  int row = blockIdx.x;
  int c = threadIdx.x * 4;
  f32x4 v = *(const f32x4*)(x + (size_t)row * C_ + c);
  float s  = v[0] + v[1] + v[2] + v[3];
  float s2 = v[0]*v[0] + v[1]*v[1] + v[2]*v[2] + v[3]*v[3];
  bredux2(s, s2, red);
  float mean = s * (1.0f / C_);
  float var  = s2 * (1.0f / C_) - mean * mean;
  float rstd = rsqrtf(var + 1e-5f);
  f32x4 wv = *(const f32x4*)(w + c);
  f32x4 bv = *(const f32x4*)(b + c);
  bf16x4 o;
#pragma unroll
  for (int j = 0; j < 4; ++j)
    o[j] = (bf16)((v[j] - mean) * rstd * wv[j] + bv[j]);
  *(bf16x4*)(out + (size_t)row * C_ + c) = o;
}

// ------------------------------------------------------------------
// final LN + head GEMV + softplus (all fp32): out[row] = softplus(ln(x)@hw+hb)
// ------------------------------------------------------------------
__global__ __launch_bounds__(256) void ln_head_k(
    const float* __restrict__ x, const float* __restrict__ w,
    const float* __restrict__ b, const float* __restrict__ hw,
    const float* __restrict__ hb, float* __restrict__ out)
{
  __shared__ float red[8];
  int row = blockIdx.x;
  int c = threadIdx.x * 4;
  f32x4 v = *(const f32x4*)(x + (size_t)row * C_ + c);
  float s  = v[0] + v[1] + v[2] + v[3];
  float s2 = v[0]*v[0] + v[1]*v[1] + v[2]*v[2] + v[3]*v[3];
  bredux2(s, s2, red);
  float mean = s * (1.0f / C_);
  float var  = s2 * (1.0f / C_) - mean * mean;
  float rstd = rsqrtf(var + 1e-5f);
  f32x4 wv = *(const f32x4*)(w + c);
  f32x4 bv = *(const f32x4*)(b + c);
  f32x4 hv = *(const f32x4*)(hw + c);
  float dot = 0.f, dummy = 0.f;
#pragma unroll
  for (int j = 0; j < 4; ++j)
    dot += ((v[j] - mean) * rstd * wv[j] + bv[j]) * hv[j];
  bredux2(dot, dummy, red);
  if (threadIdx.x == 0) {
    float z = dot + hb[0];
    float sp = z > 20.f ? z : log1pf(expf(z));
    out[row] = sp;
  }
}

// ------------------------------------------------------------------
// GEMM: C[M,N] = epilogue(A[M,K](bf16) @ W[K,N](fp32->bf16) + bias(fp32))
// 128x128 tile, BK=32, 256 thr = 4 waves (2x2), 4x4 MFMA 16x16x32 each
// ------------------------------------------------------------------
#define EPI_F32_RESID 0  // out fp32 [M,N] = v + resid (in-place resid ok)
#define EPI_BF16 1       // out bf16 [M,N]
#define EPI_BF16_GELU 2  // out bf16 [M,N], exact gelu
#define EPI_SCAT_BHTD 3  // out bf16 [B,H,T,D]
#define EPI_SCAT_BHDT 4  // out bf16 [B,H,D,T]

template <int MODE>
__global__ __launch_bounds__(256, 2) void gemm_k(
    const bf16* __restrict__ A, const float* __restrict__ W,
    const float* __restrict__ bias, const float* __restrict__ resid,
    void* __restrict__ out, int M, int N, int K)
{
  __shared__ bf16 As[128 * 32];  // [m][k]
  __shared__ bf16 Bs[128 * 32];  // [n][k] (transposed W tile)
  int tid = threadIdx.x;
  int bm = blockIdx.x, bn = blockIdx.y;
  int lane = tid & 63, wid = tid >> 6;
  int l16 = lane & 15, lq = lane >> 4;
  int wm = (wid >> 1) * 64, wn = (wid & 1) * 64;

  f32x4 acc[4][4] = {};
  const size_t a_base = (size_t)bm * 128 * K;

  for (int k0 = 0; k0 < K; k0 += 32) {
    // stage A tile: 128x32 bf16, chunks of 8 along k
#pragma unroll
    for (int i = 0; i < 2; ++i) {
      int ch = tid + i * 256;          // 0..511
      int r = ch >> 2, kc = (ch & 3) * 8;
      *(bf16x8*)(As + r * 32 + kc) =
          *(const bf16x8*)(A + a_base + (size_t)r * K + k0 + kc);
    }
    // stage B tile: W[k0..k0+32, bn*128..+128] (fp32) -> Bs[n][k] (bf16)
#pragma unroll
    for (int i = 0; i < 2; ++i) {
      int ch = tid + i * 256;          // 0..511
      int kr = ch >> 4, nc = (ch & 15) * 8;
      const float* wp = W + (size_t)(k0 + kr) * N + bn * 128 + nc;
      f32x4 w0 = *(const f32x4*)(wp);
      f32x4 w1 = *(const f32x4*)(wp + 4);
#pragma unroll
      for (int j = 0; j < 4; ++j) {
        Bs[(nc + j) * 32 + kr]     = (bf16)w0[j];
        Bs[(nc + 4 + j) * 32 + kr] = (bf16)w1[j];
      }
    }
    __syncthreads();
    bf16x8 af[4], bfr[4];
#pragma unroll
    for (int mi = 0; mi < 4; ++mi)
      af[mi] = *(const bf16x8*)(As + (wm + mi * 16 + l16) * 32 + lq * 8);
#pragma unroll
    for (int ni = 0; ni < 4; ++ni)
      bfr[ni] = *(const bf16x8*)(Bs + (wn + ni * 16 + l16) * 32 + lq * 8);
#pragma unroll
    for (int mi = 0; mi < 4; ++mi)
#pragma unroll
      for (int ni = 0; ni < 4; ++ni)
        acc[mi][ni] = __builtin_amdgcn_mfma_f32_16x16x32_bf16(
            af[mi], bfr[ni], acc[mi][ni], 0, 0, 0);
    __syncthreads();
  }

  float* outf = (float*)out;
  bf16* outb = (bf16*)out;
#pragma unroll
  for (int mi = 0; mi < 4; ++mi) {
#pragma unroll
    for (int ni = 0; ni < 4; ++ni) {
#pragma unroll
      for (int r = 0; r < 4; ++r) {
        int row = bm * 128 + wm + mi * 16 + lq * 4 + r;
        int col = bn * 128 + wn + ni * 16 + l16;
        float v = acc[mi][ni][r] + bias[col];
        if constexpr (MODE == EPI_F32_RESID) {
          size_t o = (size_t)row * N + col;
          outf[o] = v + resid[o];
        } else if constexpr (MODE == EPI_BF16) {
          outb[(size_t)row * N + col] = (bf16)v;
        } else if constexpr (MODE == EPI_BF16_GELU) {
          float g = 0.5f * v * (1.0f + erff(v * 0.70710678118f));
          outb[(size_t)row * N + col] = (bf16)g;
        } else if constexpr (MODE == EPI_SCAT_BHTD) {
          int b = row >> 9, t = row & 511, hh = col >> 6, d = col & 63;
          outb[(((size_t)(b * H_ + hh)) * T_ + t) * D_ + d] = (bf16)v;
        } else {  // EPI_SCAT_BHDT
          int b = row >> 9, t = row & 511, hh = col >> 6, d = col & 63;
          outb[(((size_t)(b * H_ + hh)) * D_ + d) * T_ + t] = (bf16)v;
        }
      }
    }
  }
}

// ------------------------------------------------------------------
// flash attention: grid (B*H, T/64), 256 thr = 4 waves, wave owns 16 q rows
// Q,K: [B*H, T, D] bf16; Vt: [B*H, D, T] bf16; Y: [B*T, C] bf16 (col=h*64+d)
// ------------------------------------------------------------------
__global__ __launch_bounds__(256, 2) void attn_k(
    const bf16* __restrict__ Q, const bf16* __restrict__ Kb,
    const bf16* __restrict__ Vt, bf16* __restrict__ Y)
{
  int bh = blockIdx.x;   // 0..255
  int qt = blockIdx.y;   // 0..7
  int tid = threadIdx.x, lane = tid & 63, wid = tid >> 6;
  int l16 = lane & 15, lq = lane >> 4;
  int qrow0 = qt * 64 + wid * 16;

  const bf16* Qp = Q + ((size_t)bh * T_ + qrow0) * D_;
  const bf16* Kp = Kb + (size_t)bh * T_ * D_;
  const bf16* Vp = Vt + (size_t)bh * D_ * T_;

  // Q fragments (A-layout), two d-halves of 32
  bf16x8 qf0 = *(const bf16x8*)(Qp + (size_t)l16 * D_ + lq * 8);
  bf16x8 qf1 = *(const bf16x8*)(Qp + (size_t)l16 * D_ + 32 + lq * 8);

  f32x4 o[4] = {};
  float mrow[4], lrow[4];
#pragma unroll
  for (int r = 0; r < 4; ++r) { mrow[r] = -1e30f; lrow[r] = 0.f; }

  __shared__ bf16 pshare[4][16 * 32];  // per-wave P tile [q][key]
  bf16* ps = pshare[wid];

  for (int kb = 0; kb < T_; kb += 32) {
    // S = Q @ K^T for 32 keys (two 16-key subtiles)
    f32x4 s0 = {}, s1 = {};
    {
      const bf16* kp0 = Kp + (size_t)(kb + l16) * D_;
      const bf16* kp1 = Kp + (size_t)(kb + 16 + l16) * D_;
      bf16x8 k00 = *(const bf16x8*)(kp0 + lq * 8);
      bf16x8 k01 = *(const bf16x8*)(kp0 + 32 + lq * 8);
      bf16x8 k10 = *(const bf16x8*)(kp1 + lq * 8);
      bf16x8 k11 = *(const bf16x8*)(kp1 + 32 + lq * 8);
      s0 = __builtin_amdgcn_mfma_f32_16x16x32_bf16(qf0, k00, s0, 0, 0, 0);
      s0 = __builtin_amdgcn_mfma_f32_16x16x32_bf16(qf1, k01, s0, 0, 0, 0);
      s1 = __builtin_amdgcn_mfma_f32_16x16x32_bf16(qf0, k10, s1, 0, 0, 0);
      s1 = __builtin_amdgcn_mfma_f32_16x16x32_bf16(qf1, k11, s1, 0, 0, 0);
    }
    float bmax[4], rs[4], alpha[4];
#pragma unroll
    for (int r = 0; r < 4; ++r) {
      s0[r] *= 0.125f; s1[r] *= 0.125f;          // 1/sqrt(64)
      bmax[r] = fmaxf(s0[r], s1[r]);
    }
#pragma unroll
    for (int off = 1; off < 16; off <<= 1)
#pragma unroll
      for (int r = 0; r < 4; ++r) bmax[r] = fmaxf(bmax[r], __shfl_xor(bmax[r], off));
#pragma unroll
    for (int r = 0; r < 4; ++r) {
      float mn = fmaxf(mrow[r], bmax[r]);
      alpha[r] = __expf(mrow[r] - mn);
      mrow[r] = mn;
      s0[r] = __expf(s0[r] - mn);
      s1[r] = __expf(s1[r] - mn);
      rs[r] = s0[r] + s1[r];
    }
#pragma unroll
    for (int off = 1; off < 16; off <<= 1)
#pragma unroll
      for (int r = 0; r < 4; ++r) rs[r] += __shfl_xor(rs[r], off);
#pragma unroll
    for (int r = 0; r < 4; ++r) lrow[r] = lrow[r] * alpha[r] + rs[r];
#pragma unroll
    for (int nt = 0; nt < 4; ++nt)
#pragma unroll
      for (int r = 0; r < 4; ++r) o[nt][r] *= alpha[r];
    // P: C-layout -> LDS -> A-layout (bf16)
#pragma unroll
    for (int r = 0; r < 4; ++r) {
      ps[(lq * 4 + r) * 32 + l16]      = (bf16)s0[r];
      ps[(lq * 4 + r) * 32 + 16 + l16] = (bf16)s1[r];
    }
    __syncthreads();
    bf16x8 pf = *(const bf16x8*)(ps + l16 * 32 + lq * 8);
    __syncthreads();
    // O += P @ V  (4 d-tiles of 16)
#pragma unroll
    for (int nt = 0; nt < 4; ++nt) {
      bf16x8 vf = *(const bf16x8*)(Vp + (size_t)(nt * 16 + l16) * T_ + kb + lq * 8);
      o[nt] = __builtin_amdgcn_mfma_f32_16x16x32_bf16(pf, vf, o[nt], 0, 0, 0);
    }
  }
  // epilogue: O/l -> Y[b*T+q, h*64+d]
  int b = bh >> 4, h = bh & 15;
#pragma unroll
  for (int nt = 0; nt < 4; ++nt) {
#pragma unroll
    for (int r = 0; r < 4; ++r) {
      int qrow = qrow0 + lq * 4 + r;
      int col = h * 64 + nt * 16 + l16;
      Y[((size_t)b * T_ + qrow) * C_ + col] = (bf16)(o[nt][r] / lrow[r]);
    }
  }
}

// ------------------------------------------------------------------
extern "C" void kernel_launch(void* const* d_in, const int* in_sizes, int n_in,
                              void* d_out, int out_size, void* d_ws, size_t ws_size,
                              hipStream_t stream)
{
  const int*   idx  = (const int*)  d_in[0];
  const float* tok  = (const float*)d_in[1];
  const float* pos  = (const float*)d_in[2];
  const float* ln1w = (const float*)d_in[3];
  const float* ln1b = (const float*)d_in[4];
  const float* ln2w = (const float*)d_in[5];
  const float* ln2b = (const float*)d_in[6];
  const float* Wq = (const float*)d_in[7];
  const float* bq = (const float*)d_in[8];
  const float* Wk = (const float*)d_in[9];
  const float* bk = (const float*)d_in[10];
  const float* Wv = (const float*)d_in[11];
  const float* bv = (const float*)d_in[12];
  const float* Wo = (const float*)d_in[13];
  const float* bo = (const float*)d_in[14];
  const float* W1 = (const float*)d_in[15];
  const float* b1 = (const float*)d_in[16];
  const float* W2 = (const float*)d_in[17];
  const float* b2 = (const float*)d_in[18];
  const float* lnfw = (const float*)d_in[19];
  const float* lnfb = (const float*)d_in[20];
  const float* hw   = (const float*)d_in[21];
  const float* hb   = (const float*)d_in[22];

  // workspace layout (176 MB total)
  char* p = (char*)d_ws;
  float* x  = (float*)p; p += (size_t)M_ * C_ * 4;   // 32 MB residual stream
  bf16* hbuf = (bf16*)p; p += (size_t)M_ * C_ * 2;   // LN out
  bf16* qb  = (bf16*)p;  p += (size_t)M_ * C_ * 2;   // [B,H,T,D]
  bf16* kbf = (bf16*)p;  p += (size_t)M_ * C_ * 2;   // [B,H,T,D]
  bf16* vtb = (bf16*)p;  p += (size_t)M_ * C_ * 2;   // [B,H,D,T]
  bf16* yb  = (bf16*)p;  p += (size_t)M_ * C_ * 2;   // attn out [M,C]
  bf16* gb  = (bf16*)p;  p += (size_t)M_ * F_ * 2;   // FFN mid
  if ((size_t)(p - (char*)d_ws) > ws_size) return;   // ws too small: bail

  embed_k<<<M_, 256, 0, stream>>>(idx, tok, pos, x);

  for (int l = 0; l < L_; ++l) {
    ln_k<<<M_, 256, 0, stream>>>(x, ln1w + (size_t)l * C_, ln1b + (size_t)l * C_, hbuf);
    gemm_k<EPI_SCAT_BHTD><<<dim3(64, 8), 256, 0, stream>>>(
        hbuf, Wq + (size_t)l * C_ * C_, bq + (size_t)l * C_, nullptr, qb, M_, C_, C_);
    gemm_k<EPI_SCAT_BHTD><<<dim3(64, 8), 256, 0, stream>>>(
        hbuf, Wk + (size_t)l * C_ * C_, bk + (size_t)l * C_, nullptr, kbf, M_, C_, C_);
    gemm_k<EPI_SCAT_BHDT><<<dim3(64, 8), 256, 0, stream>>>(
        hbuf, Wv + (size_t)l * C_ * C_, bv + (size_t)l * C_, nullptr, vtb, M_, C_, C_);
    attn_k<<<dim3(256, 8), 256, 0, stream>>>(qb, kbf, vtb, yb);
    gemm_k<EPI_F32_RESID><<<dim3(64, 8), 256, 0, stream>>>(
        yb, Wo + (size_t)l * C_ * C_, bo + (size_t)l * C_, x, x, M_, C_, C_);
    ln_k<<<M_, 256, 0, stream>>>(x, ln2w + (size_t)l * C_, ln2b + (size_t)l * C_, hbuf);
    gemm_k<EPI_BF16_GELU><<<dim3(64, 32), 256, 0, stream>>>(
        hbuf, W1 + (size_t)l * C_ * F_, b1 + (size_t)l * F_, nullptr, gb, M_, F_, C_);
    gemm_k<EPI_F32_RESID><<<dim3(64, 8), 256, 0, stream>>>(
        gb, W2 + (size_t)l * F_ * C_, b2 + (size_t)l * C_, x, x, M_, C_, F_);
  }

  ln_head_k<<<M_, 256, 0, stream>>>(x, lnfw, lnfb, hw, hb, (float*)d_out);
}